// Round 9
// baseline (260.221 us; speedup 1.0000x reference)
//
#include <hip/hip_runtime.h>
#include <hip/hip_bf16.h>
#include <stdint.h>

#define S 2048
#define HID 2048
#define NH 16
#define HD 128

typedef short short8 __attribute__((ext_vector_type(8)));
typedef float f32x4 __attribute__((ext_vector_type(4)));
typedef float f32x16 __attribute__((ext_vector_type(16)));
typedef uint32_t u32;
typedef u32 u32x4 __attribute__((ext_vector_type(4)));

__device__ __forceinline__ ushort f2bf(float x) {
  uint32_t u = __builtin_bit_cast(uint32_t, x);
  if ((u & 0x7fffffffu) > 0x7f800000u) return (ushort)((u >> 16) | 0x40);  // quiet NaN
  uint32_t r = u + 0x7fffu + ((u >> 16) & 1u);                             // RNE
  return (ushort)(r >> 16);
}
__device__ __forceinline__ float bf2f(ushort u) {
  union { uint32_t i; float f; } c; c.i = ((uint32_t)u) << 16; return c.f;
}

// async global->LDS, 16B per lane; LDS dest must be wave-uniform (HW adds lane*16)
__device__ __forceinline__ void glds16(const ushort* g, ushort* l) {
  __builtin_amdgcn_global_load_lds((const __attribute__((address_space(1))) uint32_t*)g,
                                   (__attribute__((address_space(3))) uint32_t*)l, 16, 0, 0);
}

// MFMA via inline asm (compiler can't pad MFMA->VALU hazards itself).
__device__ __forceinline__ void mfma16(f32x4& d, short8 a, short8 b) {
  asm volatile("v_mfma_f32_16x16x32_bf16 %0, %1, %2, %0" : "+v"(d) : "v"(a), "v"(b));
}
// 32x32x16 bf16: A row=lane&31,k=(lane>>5)*8+j; B col=lane&31,same k;
// D col=lane&31, row=(reg&3)+8*(reg>>2)+4*(lane>>5)
__device__ __forceinline__ void mfma32(f32x16& d, short8 a, short8 b) {
  asm volatile("v_mfma_f32_32x32x16_bf16 %0, %1, %2, %0" : "+v"(d) : "v"(a), "v"(b));
}
#define MFMA_FENCE() do {                              \
    asm volatile("s_nop 7\n\ts_nop 7\n\ts_nop 7");     \
    __builtin_amdgcn_sched_barrier(0);                 \
  } while (0)
// raw barrier: NO implicit vmcnt(0) drain (counted-vmcnt discipline, T4)
#define RAW_BARRIER() asm volatile("s_barrier" ::: "memory")
#define SCHED_FENCE() __builtin_amdgcn_sched_barrier(0)
// a' = concat(a.lo, b.lo); b' = concat(a.hi, b.hi)
__device__ __forceinline__ void plswap(u32& a, u32& b) {
  asm volatile("v_permlane32_swap_b32 %0, %1" : "+v"(a), "+v"(b));
}
__device__ __forceinline__ u32 cvtpk(float lo, float hi) {
  u32 r; asm volatile("v_cvt_pk_bf16_f32 %0, %1, %2" : "=v"(r) : "v"(lo), "v"(hi)); return r;
}

struct CastArgs { const float* s[6]; ushort* d[6]; };
__global__ __launch_bounds__(256) void cast6_k(CastArgs a) {
  const float* in = a.s[blockIdx.y];
  ushort* out = a.d[blockIdx.y];
  int i = blockIdx.x * 256 + threadIdx.x;
  float4 v = ((const float4*)in)[i];
  ushort4 o;
  o.x = f2bf(v.x); o.y = f2bf(v.y); o.z = f2bf(v.z); o.w = f2bf(v.w);
  ((ushort4*)out)[i] = o;
}

// C[m,n] = sum_k A[m,k]*B[n,k]; A:[M][K] bf16, B:[N][K] bf16.
// Double-buffered LDS + counted vmcnt + raw barriers: staged loads for k0+64
// stay in flight across both barriers, drained by vmcnt(8) one step later.
template <int OUTF32, int NSPLIT>
__global__ __launch_bounds__(256)
void gemm_bt_k(const ushort* __restrict__ A, const ushort* __restrict__ B,
               void* __restrict__ C, int M, int N, int K) {
  __shared__ __align__(16) ushort ldsA[2 * 128 * 64];
  __shared__ __align__(16) ushort ldsB[2 * 128 * 64];
  const int tid = threadIdx.x, lane = tid & 63, wid = tid >> 6;
  const int g = lane >> 4, c = lane & 15;
  const int wr = wid >> 1, wc = wid & 1;
  const long m0 = (long)blockIdx.y * 128, n0 = (long)blockIdx.x * 128;
  const int srow = lane >> 3, sslot = lane & 7;

  f32x4 acc[4][4] = {};

#define GSTAGE(BO, K0) do {                                                \
    _Pragma("unroll")                                                      \
    for (int i_ = 0; i_ < 4; ++i_) {                                       \
      int ii = wid * 4 + i_;                                               \
      int rt = ii * 8 + srow;                                              \
      int col = ((sslot ^ (rt & 7)) << 3) + (K0);                          \
      glds16(A + (m0 + rt) * (long)K + col, ldsA + (BO) * 8192 + ii * 512);\
      glds16(B + (n0 + rt) * (long)K + col, ldsB + (BO) * 8192 + ii * 512);\
    } } while (0)

  GSTAGE(0, 0);  // 8 loads outstanding

#pragma clang loop unroll(disable)
  for (int k0 = 0; k0 < K; k0 += 64) {
    const int bo = (k0 >> 6) & 1;
    // stage next K-step (dummy re-stage of k0=0 on the last step keeps
    // the vmcnt accounting uniform; its data is never read)
    GSTAGE(bo ^ 1, (k0 + 64 < K) ? (k0 + 64) : 0);
    SCHED_FENCE();
    asm volatile("s_waitcnt vmcnt(8)");  // my 8 loads for THIS k0 landed
    SCHED_FENCE();
    RAW_BARRIER();                       // all waves' k0-tile in LDS
    const ushort* la = ldsA + bo * 8192;
    const ushort* lb = ldsB + bo * 8192;
#pragma unroll
    for (int kk = 0; kk < 2; ++kk) {
      short8 af[4], bfr[4];
#pragma unroll
      for (int m = 0; m < 4; ++m) {
        int row = wr * 64 + m * 16 + c;
        af[m] = *(const short8*)(la + row * 64 + (((kk * 4 + g) ^ (row & 7)) << 3));
      }
#pragma unroll
      for (int n = 0; n < 4; ++n) {
        int row = wc * 64 + n * 16 + c;
        bfr[n] = *(const short8*)(lb + row * 64 + (((kk * 4 + g) ^ (row & 7)) << 3));
      }
#pragma unroll
      for (int m = 0; m < 4; ++m)
#pragma unroll
        for (int n = 0; n < 4; ++n) mfma16(acc[m][n], af[m], bfr[n]);
    }
    RAW_BARRIER();                       // reads done; next stage may overwrite
  }
#undef GSTAGE
  MFMA_FENCE();
#pragma unroll
  for (int m = 0; m < 4; ++m) {
#pragma unroll
    for (int r = 0; r < 4; ++r) {
      long grow = m0 + wr * 64 + m * 16 + g * 4 + r;
#pragma unroll
      for (int n = 0; n < 4; ++n) {
        long gcol = n0 + wc * 64 + n * 16 + c;
        long idx;
        if (NSPLIT) idx = ((gcol >> 11) << 22) + (grow << 11) + (gcol & 2047);
        else        idx = grow * N + gcol;
        float v = acc[m][n][r];
        if (OUTF32) ((float*)C)[idx] = bf2f(f2bf(v));
        else        ((ushort*)C)[idx] = f2bf(v);
      }
    }
  }
}

__global__ __launch_bounds__(256)
void transpose_bf16_k(const ushort* __restrict__ in, ushort* __restrict__ out) {
  __shared__ __align__(16) ushort t[64][72];
  const int tid = threadIdx.x;
  const long bx = (long)blockIdx.x * 64;
  const long by = (long)blockIdx.y * 64;
#pragma unroll
  for (int i = 0; i < 2; ++i) {
    int row = (tid >> 3) + i * 32;
    int col = (tid & 7) * 8;
    *(short8*)(&t[row][col]) = *(const short8*)(in + (by + row) * 2048 + bx + col);
  }
  __syncthreads();
#pragma unroll
  for (int i = 0; i < 2; ++i) {
    int orow = (tid >> 3) + i * 32;
    int ocol = (tid & 7) * 8;
    short8 v;
#pragma unroll
    for (int j = 0; j < 8; ++j) v[j] = (short)t[ocol + j][orow];
    *(short8*)(out + (bx + orow) * 2048 + by + ocol) = v;
  }
}

// mask [q][kv] f32  ->  maskT [kv][q] bf16 (transposed + converted).
__global__ __launch_bounds__(256)
void maskT_k(const float* __restrict__ in, ushort* __restrict__ out) {
  __shared__ ushort t[64][72];   // t[kv_local][q_local]
  const int tid = threadIdx.x;
  const long q0 = (long)blockIdx.y * 64;
  const long k0 = (long)blockIdx.x * 64;
#pragma unroll
  for (int i = 0; i < 4; ++i) {
    int row = i * 16 + (tid >> 4);   // q local
    int col = (tid & 15) * 4;        // kv local
    float4 v = *(const float4*)(in + (q0 + row) * S + k0 + col);
    t[col + 0][row] = f2bf(v.x);
    t[col + 1][row] = f2bf(v.y);
    t[col + 2][row] = f2bf(v.z);
    t[col + 3][row] = f2bf(v.w);
  }
  __syncthreads();
#pragma unroll
  for (int i = 0; i < 2; ++i) {
    int row = i * 32 + (tid >> 3);   // kv local
    int col = (tid & 7) * 8;         // q local
    *(short8*)(out + (k0 + row) * S + q0 + col) = *(const short8*)(&t[row][col]);
  }
}

// Flash attention: KVBLK=64, 4-wave blocks (q-tile 128), 2 blocks/CU, XCD-aware
// head decode, counted-vmcnt + raw-barrier pipeline (staged K/V for t+1 stay in
// flight across both barriers; drained by vmcnt(40) at t+1).
// Per-wave VMEM FIFO per tile: [8 old stages][32 mask loads][8 new stages].
// vmcnt(40) pops exactly the 8 old -> tile-t LDS valid; masks auto-waited by
// compiler at vmcnt(8) (new stages remain in flight through softmax).
// Grid: 512. Block 256 = 4 waves x 32 q-rows.
__global__ __launch_bounds__(256)
void attn6_k(const ushort* __restrict__ Qself, const ushort* __restrict__ Qcross,
             const ushort* __restrict__ Kp, const ushort* __restrict__ Vt,
             const ushort* __restrict__ maskT, ushort* __restrict__ outf) {
  __shared__ __align__(16) ushort ldsK[2 * 64 * 128];   // [buf][kv][d] 256B rows, slot^=(row&15)
  __shared__ __align__(16) ushort ldsV[2 * 128 * 64];   // [buf][d][kv] 128B rows, slot^=(row&7)
  const int tid = threadIdx.x, lane = tid & 63, wid = tid >> 6;
  const int c31 = lane & 31, hi = lane >> 5;

  const int b = blockIdx.x;
  const int xcd = b & 7, j = b >> 3;
  const int h = xcd + 8 * (j & 1);
  const int blk = (j >> 1) & 1;       // 0=self 1=cross
  const int qt = j >> 2;              // q-tile of 128 rows

  const ushort* Qp = blk ? Qcross : Qself;
  const int qbase = qt * 128 + wid * 32;
  const long qme = qbase + c31;       // this lane's q-row (owns P row q=c31)

  short8 qf[8];
#pragma unroll
  for (int ks = 0; ks < 8; ++ks)
    qf[ks] = *(const short8*)(Qp + qme * HID + h * HD + ks * 16 + hi * 8);

  f32x16 o[4] = {};   // O[q=(r&3)+8*(r>>2)+4*hi][d = dt*32 + c31]
  float m_r = -__builtin_inff(), l_r = 0.f;

  const float SC  = 0.08838834764831845f;   // 1/sqrt(128)
  const float L2E = 1.4426950408889634f;
  const float THR = 5.545177444479562f;     // 8*ln2 -> P <= 2^8

  const int kRow4 = lane >> 4, kSlot = lane & 15;
  const int vRow8 = lane >> 3, vSlot = lane & 7;
  const ushort* mT = maskT + qme;

#define STAGE(BO, KV0) do {                                                       \
    _Pragma("unroll")                                                             \
    for (int i_ = 0; i_ < 4; ++i_) {                                              \
      int seg = i_ * 4 + wid;                                                     \
      int rk = seg * 4 + kRow4;                                                   \
      glds16(Kp + (long)((KV0) + rk) * HID + h * HD + ((kSlot ^ (rk & 15)) << 3), \
             ldsK + (BO) * 8192 + seg * 512);                                     \
      int rv = seg * 8 + vRow8;                                                   \
      glds16(Vt + (long)(h * HD + rv) * S + (KV0) + ((vSlot ^ (rv & 7)) << 3),    \
             ldsV + (BO) * 8192 + seg * 512);                                     \
    }                                                                             \
  } while (0)

  STAGE(0, 0);  // prologue: 8 loads outstanding

#pragma clang loop unroll(disable)
  for (int t = 0; t < 32; ++t) {
    const int bo = t & 1;
    const ushort* kb = ldsK + bo * 8192;
    const ushort* vb = ldsV + bo * 8192;
    const int kv0 = t * 64;

    // 1. mask loads (32 scalar bf16) — consumed in softmax, compiler-waited
    ushort mvu0[16], mvu1[16];
#pragma unroll
    for (int r = 0; r < 16; ++r) {
      int krow = (r & 3) + 8 * (r >> 2) + 4 * hi;
      mvu0[r] = mT[(long)(kv0 + krow) * S];
      mvu1[r] = mT[(long)(kv0 + 32 + krow) * S];
    }
    SCHED_FENCE();
    // 2. stage tile t+1 (dummy wrap on last tile keeps accounting uniform)
    STAGE(bo ^ 1, ((t + 1) & 31) * 64);
    SCHED_FENCE();
    // 3. my 8 tile-t loads landed (masks + new stages stay in flight)
    asm volatile("s_waitcnt vmcnt(40)");
    SCHED_FENCE();
    // 4. all waves' tile-t data in LDS
    RAW_BARRIER();

    // 5. S^T = K @ Q^T : lane holds S[q=c31][kv = kvb*32 + (r&3)+8*(r>>2)+4*hi]
    f32x16 s0 = {}, s1 = {};
    __builtin_amdgcn_s_setprio(1);
#pragma unroll
    for (int ks = 0; ks < 8; ++ks) {
      int r0 = c31, r1 = 32 + c31;
      short8 kf0 = *(const short8*)(kb + r0 * 128 + (((ks * 2 + hi) ^ (r0 & 15)) << 3));
      short8 kf1 = *(const short8*)(kb + r1 * 128 + (((ks * 2 + hi) ^ (r1 & 15)) << 3));
      mfma32(s0, kf0, qf[ks]);
      mfma32(s1, kf1, qf[ks]);
    }
    __builtin_amdgcn_s_setprio(0);
    MFMA_FENCE();  // s0/s1 read by VALU below

    // natural domain: tv = s*scale + mask  (one FMA per element)
#pragma unroll
    for (int r = 0; r < 16; ++r) {
      s0[r] = __builtin_fmaf(s0[r], SC, bf2f(mvu0[r]));
      s1[r] = __builtin_fmaf(s1[r], SC, bf2f(mvu1[r]));
    }

    // row max: pairwise tree + cross-half exchange
    float mx[16];
#pragma unroll
    for (int r = 0; r < 16; ++r) mx[r] = fmaxf(s0[r], s1[r]);
#pragma unroll
    for (int st = 8; st >= 1; st >>= 1)
#pragma unroll
      for (int i = 0; i < 8; ++i)
        if (i < st) mx[i] = fmaxf(mx[i], mx[i + st]);
    float pmax = fmaxf(mx[0], __shfl_xor(mx[0], 32));

    // defer-max: rescale O and l only when max grows by > THR (wave-uniform)
    if (!__all(pmax <= m_r + THR)) {
      float mnew = fmaxf(m_r, pmax);
      float alpha = __builtin_amdgcn_exp2f((m_r - mnew) * L2E);  // 0 on first tile
      m_r = mnew;
      l_r *= alpha;
#pragma unroll
      for (int r = 0; r < 16; ++r) {
        float alf = __shfl(alpha, (r & 3) + 8 * (r >> 2) + 4 * hi);
#pragma unroll
        for (int dt = 0; dt < 4; ++dt) o[dt][r] *= alf;
      }
    }

    // P = exp(tv - m); f32 row-sum via tree (matches ref denom)
    const float nm = -m_r * L2E;
#pragma unroll
    for (int r = 0; r < 16; ++r) {
      s0[r] = __builtin_amdgcn_exp2f(__builtin_fmaf(s0[r], L2E, nm));
      s1[r] = __builtin_amdgcn_exp2f(__builtin_fmaf(s1[r], L2E, nm));
    }
    float sm[16];
#pragma unroll
    for (int r = 0; r < 16; ++r) sm[r] = s0[r] + s1[r];
#pragma unroll
    for (int st = 8; st >= 1; st >>= 1)
#pragma unroll
      for (int i = 0; i < 8; ++i)
        if (i < st) sm[i] += sm[i + st];
    l_r += sm[0] + __shfl_xor(sm[0], 32);

    // P -> bf16 A-frags: per 16-kv block, 4 cvt_pk + 2 permlane32_swap
    short8 pa[4];
#pragma unroll
    for (int kk = 0; kk < 4; ++kk) {
      const f32x16& sv = (kk < 2) ? s0 : s1;
      const int bq = (kk & 1) * 8;
      u32 x0 = cvtpk(sv[bq + 0], sv[bq + 1]);
      u32 x1 = cvtpk(sv[bq + 2], sv[bq + 3]);
      u32 y0 = cvtpk(sv[bq + 4], sv[bq + 5]);
      u32 y1 = cvtpk(sv[bq + 6], sv[bq + 7]);
      plswap(x0, y0);
      plswap(x1, y1);
      u32x4 tt; tt[0] = x0; tt[1] = x1; tt[2] = y0; tt[3] = y1;
      pa[kk] = __builtin_bit_cast(short8, tt);
    }
    // VALU(permlane) -> MFMA SrcA hazard padding
    asm volatile("s_nop 1");
    SCHED_FENCE();

    // O += P @ V
    __builtin_amdgcn_s_setprio(1);
#pragma unroll
    for (int dt = 0; dt < 4; ++dt) {
      int row = dt * 32 + c31;
#pragma unroll
      for (int kk = 0; kk < 4; ++kk) {
        short8 vf = *(const short8*)(vb + row * 64 + (((kk * 2 + hi) ^ (row & 7)) << 3));
        mfma32(o[dt], pa[kk], vf);
      }
    }
    __builtin_amdgcn_s_setprio(0);

    // 8. reads of tile-t buffers done; next body may overwrite
    RAW_BARRIER();
  }
#undef STAGE

  MFMA_FENCE();  // o[] read by VALU epilogue
#pragma unroll
  for (int r = 0; r < 16; ++r) {
    int qr = (r & 3) + 8 * (r >> 2) + 4 * hi;
    float linv = 1.0f / __shfl(l_r, qr);
    long orow = 2L * (qbase + qr) + blk;
#pragma unroll
    for (int dt = 0; dt < 4; ++dt)
      outf[orow * HID + h * HD + dt * 32 + c31] = f2bf(o[dt][r] * linv);
  }
}

extern "C" void kernel_launch(void* const* d_in, const int* in_sizes, int n_in,
                              void* d_out, int out_size, void* d_ws, size_t ws_size,
                              hipStream_t stream) {
  (void)in_sizes; (void)n_in; (void)out_size; (void)ws_size;
  const float* x_self  = (const float*)d_in[0];
  const float* x_cross = (const float*)d_in[1];
  const float* mask    = (const float*)d_in[2];
  const float* Wq      = (const float*)d_in[3];
  const float* Wk      = (const float*)d_in[4];
  const float* Wv      = (const float*)d_in[5];
  const float* Wo      = (const float*)d_in[6];

  uint8_t* w = (uint8_t*)d_ws;
  const size_t MB8 = (size_t)S * HID * sizeof(ushort);  // 8 MiB
  ushort* xs_bf   = (ushort*)(w + 0 * MB8);  // later reused as Vt
  ushort* xc_bf   = (ushort*)(w + 1 * MB8);
  ushort* Wq_bf   = (ushort*)(w + 2 * MB8);  // later reused as out_flat (16MB w/ Wk)
  ushort* Wk_bf   = (ushort*)(w + 3 * MB8);
  ushort* Wv_bf   = (ushort*)(w + 4 * MB8);
  ushort* Wo_bf   = (ushort*)(w + 5 * MB8);
  ushort* q_self  = (ushort*)(w + 6 * MB8);
  ushort* q_cross = (ushort*)(w + 7 * MB8);
  ushort* k_      = (ushort*)(w + 8 * MB8);
  ushort* v_      = (ushort*)(w + 9 * MB8);
  ushort* vt       = xs_bf;   // alias: xs/xc dead after projections
  ushort* out_flat = Wq_bf;   // alias: Wq/Wk bf16 dead after projections
  ushort* maskT    = v_;      // alias: v_ dead after V-transpose

  CastArgs ca;
  ca.s[0] = x_self;  ca.d[0] = xs_bf;
  ca.s[1] = x_cross; ca.d[1] = xc_bf;
  ca.s[2] = Wq;      ca.d[2] = Wq_bf;
  ca.s[3] = Wk;      ca.d[3] = Wk_bf;
  ca.s[4] = Wv;      ca.d[4] = Wv_bf;
  ca.s[5] = Wo;      ca.d[5] = Wo_bf;
  cast6_k<<<dim3(4096, 6), 256, 0, stream>>>(ca);

  gemm_bt_k<0, 0><<<dim3(16, 32), 256, 0, stream>>>(xs_bf, Wq_bf, q_self, 4096, 2048, 2048);
  gemm_bt_k<0, 1><<<dim3(32, 16), 256, 0, stream>>>(xs_bf, Wk_bf, k_, 2048, 4096, 2048);

  transpose_bf16_k<<<dim3(32, 32), 256, 0, stream>>>(v_, vt);
  maskT_k<<<dim3(32, 32), 256, 0, stream>>>(mask, maskT);  // after v_ consumed

  attn6_k<<<dim3(512), 256, 0, stream>>>(q_self, q_cross, k_, vt, maskT, out_flat);

  gemm_bt_k<1, 0><<<dim3(16, 32), 256, 0, stream>>>(out_flat, Wo_bf, d_out, 4096, 2048, 2048);
}

// Round 10
// 245.752 us; speedup vs baseline: 1.0589x; 1.0589x over previous
//
#include <hip/hip_runtime.h>
#include <hip/hip_bf16.h>
#include <stdint.h>

#define S 2048
#define HID 2048
#define NH 16
#define HD 128

typedef short short8 __attribute__((ext_vector_type(8)));
typedef float f32x4 __attribute__((ext_vector_type(4)));
typedef float f32x16 __attribute__((ext_vector_type(16)));
typedef uint32_t u32;
typedef u32 u32x4 __attribute__((ext_vector_type(4)));

__device__ __forceinline__ ushort f2bf(float x) {
  uint32_t u = __builtin_bit_cast(uint32_t, x);
  if ((u & 0x7fffffffu) > 0x7f800000u) return (ushort)((u >> 16) | 0x40);  // quiet NaN
  uint32_t r = u + 0x7fffu + ((u >> 16) & 1u);                             // RNE
  return (ushort)(r >> 16);
}
__device__ __forceinline__ float bf2f(ushort u) {
  union { uint32_t i; float f; } c; c.i = ((uint32_t)u) << 16; return c.f;
}

// async global->LDS, 16B per lane; LDS dest must be wave-uniform (HW adds lane*16)
__device__ __forceinline__ void glds16(const ushort* g, ushort* l) {
  __builtin_amdgcn_global_load_lds((const __attribute__((address_space(1))) uint32_t*)g,
                                   (__attribute__((address_space(3))) uint32_t*)l, 16, 0, 0);
}

// MFMA via inline asm (compiler can't pad MFMA->VALU hazards itself).
__device__ __forceinline__ void mfma16(f32x4& d, short8 a, short8 b) {
  asm volatile("v_mfma_f32_16x16x32_bf16 %0, %1, %2, %0" : "+v"(d) : "v"(a), "v"(b));
}
// 32x32x16 bf16: A row=lane&31,k=(lane>>5)*8+j; B col=lane&31,same k;
// D col=lane&31, row=(reg&3)+8*(reg>>2)+4*(lane>>5)
__device__ __forceinline__ void mfma32(f32x16& d, short8 a, short8 b) {
  asm volatile("v_mfma_f32_32x32x16_bf16 %0, %1, %2, %0" : "+v"(d) : "v"(a), "v"(b));
}
#define MFMA_FENCE() do {                              \
    asm volatile("s_nop 7\n\ts_nop 7\n\ts_nop 7");     \
    __builtin_amdgcn_sched_barrier(0);                 \
  } while (0)
#define RAW_BARRIER() asm volatile("s_barrier" ::: "memory")
#define SCHED_FENCE() __builtin_amdgcn_sched_barrier(0)
#define MAX3(a, b, c) fmaxf(fmaxf((a), (b)), (c))
// a' = concat(a.lo, b.lo); b' = concat(a.hi, b.hi)
__device__ __forceinline__ void plswap(u32& a, u32& b) {
  asm volatile("v_permlane32_swap_b32 %0, %1" : "+v"(a), "+v"(b));
}
__device__ __forceinline__ u32 cvtpk(float lo, float hi) {
  u32 r; asm volatile("v_cvt_pk_bf16_f32 %0, %1, %2" : "=v"(r) : "v"(lo), "v"(hi)); return r;
}

struct CastArgs { const float* s[6]; ushort* d[6]; };
__global__ __launch_bounds__(256) void cast6_k(CastArgs a) {
  const float* in = a.s[blockIdx.y];
  ushort* out = a.d[blockIdx.y];
  int i = blockIdx.x * 256 + threadIdx.x;
  float4 v = ((const float4*)in)[i];
  ushort4 o;
  o.x = f2bf(v.x); o.y = f2bf(v.y); o.z = f2bf(v.z); o.w = f2bf(v.w);
  ((ushort4*)out)[i] = o;
}

// C[m,n] = sum_k A[m,k]*B[n,k]; A:[M][K] bf16, B:[N][K] bf16.  (round-7 form:
// 32KB LDS single-buffer + __syncthreads — measured faster than 64KB dbuf.)
template <int OUTF32, int NSPLIT>
__global__ __launch_bounds__(256)
void gemm_bt_k(const ushort* __restrict__ A, const ushort* __restrict__ B,
               void* __restrict__ C, int M, int N, int K) {
  __shared__ __align__(16) ushort ldsA[128 * 64];
  __shared__ __align__(16) ushort ldsB[128 * 64];
  const int tid = threadIdx.x, lane = tid & 63, wid = tid >> 6;
  const int g = lane >> 4, c = lane & 15;
  const int wr = wid >> 1, wc = wid & 1;
  const long m0 = (long)blockIdx.y * 128, n0 = (long)blockIdx.x * 128;
  const int srow = lane >> 3, sslot = lane & 7;

  f32x4 acc[4][4] = {};

  for (int k0 = 0; k0 < K; k0 += 64) {
#pragma unroll
    for (int i = 0; i < 4; ++i) {
      int ii = wid * 4 + i;
      int rt = ii * 8 + srow;
      int col = ((sslot ^ (rt & 7)) << 3) + k0;
      glds16(A + (m0 + rt) * (long)K + col, ldsA + ii * 512);
      glds16(B + (n0 + rt) * (long)K + col, ldsB + ii * 512);
    }
    __syncthreads();
#pragma unroll
    for (int kk = 0; kk < 2; ++kk) {
      short8 af[4], bfr[4];
#pragma unroll
      for (int m = 0; m < 4; ++m) {
        int row = wr * 64 + m * 16 + c;
        af[m] = *(const short8*)(ldsA + row * 64 + (((kk * 4 + g) ^ (row & 7)) << 3));
      }
#pragma unroll
      for (int n = 0; n < 4; ++n) {
        int row = wc * 64 + n * 16 + c;
        bfr[n] = *(const short8*)(ldsB + row * 64 + (((kk * 4 + g) ^ (row & 7)) << 3));
      }
#pragma unroll
      for (int m = 0; m < 4; ++m)
#pragma unroll
        for (int n = 0; n < 4; ++n) mfma16(acc[m][n], af[m], bfr[n]);
    }
    __syncthreads();
  }
  MFMA_FENCE();
#pragma unroll
  for (int m = 0; m < 4; ++m) {
#pragma unroll
    for (int r = 0; r < 4; ++r) {
      long grow = m0 + wr * 64 + m * 16 + g * 4 + r;
#pragma unroll
      for (int n = 0; n < 4; ++n) {
        long gcol = n0 + wc * 64 + n * 16 + c;
        long idx;
        if (NSPLIT) idx = ((gcol >> 11) << 22) + (grow << 11) + (gcol & 2047);
        else        idx = grow * N + gcol;
        float v = acc[m][n][r];
        if (OUTF32) ((float*)C)[idx] = bf2f(f2bf(v));
        else        ((ushort*)C)[idx] = f2bf(v);
      }
    }
  }
}

__global__ __launch_bounds__(256)
void transpose_bf16_k(const ushort* __restrict__ in, ushort* __restrict__ out) {
  __shared__ __align__(16) ushort t[64][72];
  const int tid = threadIdx.x;
  const long bx = (long)blockIdx.x * 64;
  const long by = (long)blockIdx.y * 64;
#pragma unroll
  for (int i = 0; i < 2; ++i) {
    int row = (tid >> 3) + i * 32;
    int col = (tid & 7) * 8;
    *(short8*)(&t[row][col]) = *(const short8*)(in + (by + row) * 2048 + bx + col);
  }
  __syncthreads();
#pragma unroll
  for (int i = 0; i < 2; ++i) {
    int orow = (tid >> 3) + i * 32;
    int ocol = (tid & 7) * 8;
    short8 v;
#pragma unroll
    for (int j = 0; j < 8; ++j) v[j] = (short)t[ocol + j][orow];
    *(short8*)(out + (bx + orow) * 2048 + by + ocol) = v;
  }
}

// mask [q][kv] f32 -> maskQ [kv/4][q][4] bf16 (quad-packed transpose).
// attn lane then loads its 4 consecutive-kv mask values as ONE 8B load.
__global__ __launch_bounds__(256)
void maskQ_k(const float* __restrict__ in, ushort* __restrict__ out) {
  __shared__ ushort t[64][72];   // t[kv_local][q_local]
  const int tid = threadIdx.x;
  const long q0 = (long)blockIdx.y * 64;
  const long k0 = (long)blockIdx.x * 64;
#pragma unroll
  for (int i = 0; i < 4; ++i) {
    int row = i * 16 + (tid >> 4);   // q local
    int col = (tid & 15) * 4;        // kv local
    float4 v = *(const float4*)(in + (q0 + row) * S + k0 + col);
    t[col + 0][row] = f2bf(v.x);
    t[col + 1][row] = f2bf(v.y);
    t[col + 2][row] = f2bf(v.z);
    t[col + 3][row] = f2bf(v.w);
  }
  __syncthreads();
#pragma unroll
  for (int i = 0; i < 4; ++i) {
    int r4 = i * 4 + (tid >> 6);     // quad row 0..15
    int q = tid & 63;                // q local
    ushort4 o;
    o.x = t[r4 * 4 + 0][q];
    o.y = t[r4 * 4 + 1][q];
    o.z = t[r4 * 4 + 2][q];
    o.w = t[r4 * 4 + 3][q];
    *(ushort4*)(out + ((k0 >> 2) + r4) * (S * 4) + (q0 + q) * 4) = o;
  }
}

// Flash attention: KVBLK=64, 4-wave blocks (q-tile 128), 2 blocks/CU, XCD-aware
// head decode, counted-vmcnt + raw-barrier pipeline, quad-packed mask loads
// (8 x 8B instead of 32 scalars), kk-outer PV (dep distance 4, no MFMA bubbles).
// Per-wave VMEM FIFO per tile: [8 old stages][8 mask quads][8 new stages]
// -> vmcnt(16) pops exactly the 8 old. Grid: 512. Block 256 = 4 waves x 32 q.
__global__ __launch_bounds__(256)
void attn7_k(const ushort* __restrict__ Qself, const ushort* __restrict__ Qcross,
             const ushort* __restrict__ Kp, const ushort* __restrict__ Vt,
             const ushort* __restrict__ maskQ, ushort* __restrict__ outf) {
  __shared__ __align__(16) ushort ldsK[2 * 64 * 128];   // [buf][kv][d] 256B rows, slot^=(row&15)
  __shared__ __align__(16) ushort ldsV[2 * 128 * 64];   // [buf][d][kv] 128B rows, slot^=(row&7)
  const int tid = threadIdx.x, lane = tid & 63, wid = tid >> 6;
  const int c31 = lane & 31, hi = lane >> 5;

  const int b = blockIdx.x;
  const int xcd = b & 7, j = b >> 3;
  const int h = xcd + 8 * (j & 1);
  const int blk = (j >> 1) & 1;       // 0=self 1=cross
  const int qt = j >> 2;              // q-tile of 128 rows

  const ushort* Qp = blk ? Qcross : Qself;
  const int qbase = qt * 128 + wid * 32;
  const long qme = qbase + c31;       // this lane's q-row (owns P row q=c31)

  short8 qf[8];
#pragma unroll
  for (int ks = 0; ks < 8; ++ks)
    qf[ks] = *(const short8*)(Qp + qme * HID + h * HD + ks * 16 + hi * 8);

  f32x16 o[4] = {};   // O[q=(r&3)+8*(r>>2)+4*hi][d = dt*32 + c31]
  float m_r = -__builtin_inff(), l_r = 0.f;

  const float SC  = 0.08838834764831845f;   // 1/sqrt(128)
  const float L2E = 1.4426950408889634f;
  const float THR = 5.545177444479562f;     // 8*ln2 -> P <= 2^8

  const int kRow4 = lane >> 4, kSlot = lane & 15;
  const int vRow8 = lane >> 3, vSlot = lane & 7;
  // quad-packed mask pointer: lane's q column, hi picks kv+4 quad row
  const ushort* mqp = maskQ + qme * 4 + hi * (S * 4);

#define STAGE(BO, KV0) do {                                                       \
    _Pragma("unroll")                                                             \
    for (int i_ = 0; i_ < 4; ++i_) {                                              \
      int seg = i_ * 4 + wid;                                                     \
      int rk = seg * 4 + kRow4;                                                   \
      glds16(Kp + (long)((KV0) + rk) * HID + h * HD + ((kSlot ^ (rk & 15)) << 3), \
             ldsK + (BO) * 8192 + seg * 512);                                     \
      int rv = seg * 8 + vRow8;                                                   \
      glds16(Vt + (long)(h * HD + rv) * S + (KV0) + ((vSlot ^ (rv & 7)) << 3),    \
             ldsV + (BO) * 8192 + seg * 512);                                     \
    }                                                                             \
  } while (0)

  STAGE(0, 0);  // prologue: 8 loads outstanding

#pragma clang loop unroll(disable)
  for (int t = 0; t < 32; ++t) {
    const int bo = t & 1;
    const ushort* kb = ldsK + bo * 8192;
    const ushort* vb = ldsV + bo * 8192;

    // 1. mask quads: 8 x 8B coalesced loads; jj&3 -> kv octet, jj>>2 -> kv+32
    ushort4 mq4[8];
#pragma unroll
    for (int jj = 0; jj < 8; ++jj)
      mq4[jj] = *(const ushort4*)(mqp + ((jj & 3) * 2 + (jj >> 2) * 8) * (S * 4));
    SCHED_FENCE();
    // 2. stage tile t+1 (dummy wrap on last tile keeps accounting uniform)
    STAGE(bo ^ 1, ((t + 1) & 31) * 64);
    SCHED_FENCE();
    // 3. my 8 tile-t loads landed (mask quads + new stages stay in flight)
    asm volatile("s_waitcnt vmcnt(16)");
    SCHED_FENCE();
    // 4. all waves' tile-t data in LDS
    RAW_BARRIER();

    // 5. S^T = K @ Q^T : lane holds S[q=c31][kv = kvb*32 + (r&3)+8*(r>>2)+4*hi]
    f32x16 s0 = {}, s1 = {};
    __builtin_amdgcn_s_setprio(1);
#pragma unroll
    for (int ks = 0; ks < 8; ++ks) {
      int r0 = c31, r1 = 32 + c31;
      short8 kf0 = *(const short8*)(kb + r0 * 128 + (((ks * 2 + hi) ^ (r0 & 15)) << 3));
      short8 kf1 = *(const short8*)(kb + r1 * 128 + (((ks * 2 + hi) ^ (r1 & 15)) << 3));
      mfma32(s0, kf0, qf[ks]);
      mfma32(s1, kf1, qf[ks]);
    }
    __builtin_amdgcn_s_setprio(0);
    MFMA_FENCE();  // s0/s1 read by VALU below

    // natural domain: tv = s*scale + mask  (one FMA; mask unpack = 1 shift/and)
#pragma unroll
    for (int r = 0; r < 16; ++r) {
      s0[r] = __builtin_fmaf(s0[r], SC, bf2f(mq4[r >> 2][r & 3]));
      s1[r] = __builtin_fmaf(s1[r], SC, bf2f(mq4[4 + (r >> 2)][r & 3]));
    }

    // row max: max3-fused reduction + cross-half exchange
    float a0 = MAX3(s0[0], s0[1], s0[2]);
    float a1 = MAX3(s0[3], s0[4], s0[5]);
    float a2 = MAX3(s0[6], s0[7], s0[8]);
    float a3 = MAX3(s0[9], s0[10], s0[11]);
    float a4 = MAX3(s0[12], s0[13], s0[14]);
    float a5 = MAX3(s0[15], s1[0], s1[1]);
    float a6 = MAX3(s1[2], s1[3], s1[4]);
    float a7 = MAX3(s1[5], s1[6], s1[7]);
    float a8 = MAX3(s1[8], s1[9], s1[10]);
    float a9 = MAX3(s1[11], s1[12], s1[13]);
    float a10 = fmaxf(s1[14], s1[15]);
    float b0 = MAX3(a0, a1, a2);
    float b1 = MAX3(a3, a4, a5);
    float b2 = MAX3(a6, a7, a8);
    float b3 = fmaxf(a9, a10);
    float pm = MAX3(b0, b1, fmaxf(b2, b3));
    float pmax = fmaxf(pm, __shfl_xor(pm, 32));

    // defer-max: rescale O and l only when max grows by > THR (wave-uniform)
    if (!__all(pmax <= m_r + THR)) {
      float mnew = fmaxf(m_r, pmax);
      float alpha = __builtin_amdgcn_exp2f((m_r - mnew) * L2E);  // 0 on first tile
      m_r = mnew;
      l_r *= alpha;
#pragma unroll
      for (int r = 0; r < 16; ++r) {
        float alf = __shfl(alpha, (r & 3) + 8 * (r >> 2) + 4 * hi);
#pragma unroll
        for (int dt = 0; dt < 4; ++dt) o[dt][r] *= alf;
      }
    }

    // P = exp(tv - m); f32 row-sum via tree (matches ref denom)
    const float nm = -m_r * L2E;
#pragma unroll
    for (int r = 0; r < 16; ++r) {
      s0[r] = __builtin_amdgcn_exp2f(__builtin_fmaf(s0[r], L2E, nm));
      s1[r] = __builtin_amdgcn_exp2f(__builtin_fmaf(s1[r], L2E, nm));
    }
    float sm[16];
#pragma unroll
    for (int r = 0; r < 16; ++r) sm[r] = s0[r] + s1[r];
#pragma unroll
    for (int st = 8; st >= 1; st >>= 1)
#pragma unroll
      for (int i = 0; i < 8; ++i)
        if (i < st) sm[i] += sm[i + st];
    l_r += sm[0] + __shfl_xor(sm[0], 32);

    // P -> bf16 A-frags: per 16-kv block, 4 cvt_pk + 2 permlane32_swap
    short8 pa[4];
#pragma unroll
    for (int kk = 0; kk < 4; ++kk) {
      const f32x16& sv = (kk < 2) ? s0 : s1;
      const int bq = (kk & 1) * 8;
      u32 x0 = cvtpk(sv[bq + 0], sv[bq + 1]);
      u32 x1 = cvtpk(sv[bq + 2], sv[bq + 3]);
      u32 y0 = cvtpk(sv[bq + 4], sv[bq + 5]);
      u32 y1 = cvtpk(sv[bq + 6], sv[bq + 7]);
      plswap(x0, y0);
      plswap(x1, y1);
      u32x4 tt; tt[0] = x0; tt[1] = x1; tt[2] = y0; tt[3] = y1;
      pa[kk] = __builtin_bit_cast(short8, tt);
    }
    // VALU(permlane) -> MFMA SrcA hazard padding
    asm volatile("s_nop 1");
    SCHED_FENCE();

    // O += P @ V  (kk-outer: each o[dt] chain has dep distance 4 -> no bubbles)
    __builtin_amdgcn_s_setprio(1);
#pragma unroll
    for (int kk = 0; kk < 4; ++kk) {
#pragma unroll
      for (int dt = 0; dt < 4; ++dt) {
        int row = dt * 32 + c31;
        short8 vf = *(const short8*)(vb + row * 64 + (((kk * 2 + hi) ^ (row & 7)) << 3));
        mfma32(o[dt], pa[kk], vf);
      }
    }
    __builtin_amdgcn_s_setprio(0);

    // reads of tile-t buffers done; next body may overwrite
    RAW_BARRIER();
    mqp += 16 * (S * 4);   // advance 64 kv = 16 quad rows
  }
#undef STAGE

  MFMA_FENCE();  // o[] read by VALU epilogue
#pragma unroll
  for (int r = 0; r < 16; ++r) {
    int qr = (r & 3) + 8 * (r >> 2) + 4 * hi;
    float linv = 1.0f / __shfl(l_r, qr);
    long orow = 2L * (qbase + qr) + blk;
#pragma unroll
    for (int dt = 0; dt < 4; ++dt)
      outf[orow * HID + h * HD + dt * 32 + c31] = f2bf(o[dt][r] * linv);
  }
}

extern "C" void kernel_launch(void* const* d_in, const int* in_sizes, int n_in,
                              void* d_out, int out_size, void* d_ws, size_t ws_size,
                              hipStream_t stream) {
  (void)in_sizes; (void)n_in; (void)out_size; (void)ws_size;
  const float* x_self  = (const float*)d_in[0];
  const float* x_cross = (const float*)d_in[1];
  const float* mask    = (const float*)d_in[2];
  const float* Wq      = (const float*)d_in[3];
  const float* Wk      = (const float*)d_in[4];
  const float* Wv      = (const float*)d_in[5];
  const float* Wo      = (const float*)d_in[6];

  uint8_t* w = (uint8_t*)d_ws;
  const size_t MB8 = (size_t)S * HID * sizeof(ushort);  // 8 MiB
  ushort* xs_bf   = (ushort*)(w + 0 * MB8);  // later reused as Vt
  ushort* xc_bf   = (ushort*)(w + 1 * MB8);
  ushort* Wq_bf   = (ushort*)(w + 2 * MB8);  // later reused as out_flat (16MB w/ Wk)
  ushort* Wk_bf   = (ushort*)(w + 3 * MB8);
  ushort* Wv_bf   = (ushort*)(w + 4 * MB8);
  ushort* Wo_bf   = (ushort*)(w + 5 * MB8);
  ushort* q_self  = (ushort*)(w + 6 * MB8);
  ushort* q_cross = (ushort*)(w + 7 * MB8);
  ushort* k_      = (ushort*)(w + 8 * MB8);
  ushort* v_      = (ushort*)(w + 9 * MB8);
  ushort* vt       = xs_bf;   // alias: xs/xc dead after projections
  ushort* out_flat = Wq_bf;   // alias: Wq/Wk bf16 dead after projections
  ushort* maskQ    = v_;      // alias: v_ dead after V-transpose

  CastArgs ca;
  ca.s[0] = x_self;  ca.d[0] = xs_bf;
  ca.s[1] = x_cross; ca.d[1] = xc_bf;
  ca.s[2] = Wq;      ca.d[2] = Wq_bf;
  ca.s[3] = Wk;      ca.d[3] = Wk_bf;
  ca.s[4] = Wv;      ca.d[4] = Wv_bf;
  ca.s[5] = Wo;      ca.d[5] = Wo_bf;
  cast6_k<<<dim3(4096, 6), 256, 0, stream>>>(ca);

  gemm_bt_k<0, 0><<<dim3(16, 32), 256, 0, stream>>>(xs_bf, Wq_bf, q_self, 4096, 2048, 2048);
  gemm_bt_k<0, 1><<<dim3(32, 16), 256, 0, stream>>>(xs_bf, Wk_bf, k_, 2048, 4096, 2048);

  transpose_bf16_k<<<dim3(32, 32), 256, 0, stream>>>(v_, vt);
  maskQ_k<<<dim3(32, 32), 256, 0, stream>>>(mask, maskQ);  // after v_ consumed

  attn7_k<<<dim3(512), 256, 0, stream>>>(q_self, q_cross, k_, vt, maskQ, out_flat);

  gemm_bt_k<1, 0><<<dim3(16, 32), 256, 0, stream>>>(out_flat, Wo_bf, d_out, 4096, 2048, 2048);
}